// Round 1
// baseline (324.423 us; speedup 1.0000x reference)
//
#include <hip/hip_runtime.h>
#include <math.h>

typedef __bf16 bf16;
typedef __attribute__((ext_vector_type(4))) __bf16 bf16x4;
typedef __attribute__((ext_vector_type(8))) __bf16 bf16x8;
typedef __attribute__((ext_vector_type(4))) float f32x4;

#define AS1 __attribute__((address_space(1)))
#define AS3 __attribute__((address_space(3)))

__device__ __forceinline__ void gload16(const void* g, void* l) {
  __builtin_amdgcn_global_load_lds((const AS1 void*)g, (AS3 void*)l, 16, 0, 0);
}

#define DIM 768
#define NH  12
#define HD  64
#define B_  4
#define N_  2048
#define M_  (B_*N_)   // 8192 tokens
#define BH_ (B_*NH)   // 48 (b,h) pairs

// ---------------------------------------------------------------- convert
__global__ void convert_all(const float4* __restrict__ x,
                            const float4* __restrict__ wq,
                            const float4* __restrict__ wp,
                            bf16x4* __restrict__ xb,
                            bf16x4* __restrict__ wqb,
                            bf16x4* __restrict__ wpb) {
  const int nx = M_*DIM/4, nq = 3*DIM*DIM/4, np = DIM*DIM/4;
  const int total = nx + nq + np;
  for (int i = blockIdx.x*blockDim.x + threadIdx.x; i < total;
       i += gridDim.x*blockDim.x) {
    float4 v; bf16x4* dst;
    if (i < nx)           { v = x[i];         dst = xb  + i;         }
    else if (i < nx + nq) { v = wq[i-nx];     dst = wqb + (i-nx);    }
    else                  { v = wp[i-nx-nq];  dst = wpb + (i-nx-nq); }
    bf16x4 o = { (bf16)v.x, (bf16)v.y, (bf16)v.z, (bf16)v.w };
    *dst = o;
  }
}

// ---------------------------------------------------------------- GEMM (B^T)
// C[m][n] = sum_k A[m][k]*B[n][k];  A:[M][768] bf16, B:[N][768] bf16 row-major.
// 128x128 tile, BK=32, 4 waves (2x2 of 64x64), m97 structure.
// EPI 0: N=2304 -> scatter q (scaled), k, v^T per head.  EPI 1: N=768 -> +bias, fp32 out.
template<int EPI>
__global__ __launch_bounds__(256)
void gemm_bt(const bf16* __restrict__ A, const bf16* __restrict__ B,
             bf16* __restrict__ qv, bf16* __restrict__ kv_, bf16* __restrict__ vt,
             const float* __restrict__ bprj, float* __restrict__ out) {
  constexpr int K = DIM;
  __shared__ __align__(16) bf16 As[128*32];
  __shared__ __align__(16) bf16 Bs[128*32];
  const int tid = threadIdx.x;
  const int wave = tid >> 6, lane = tid & 63;
  const int l15 = lane & 15, lg = lane >> 4;
  const int wr = wave >> 1, wc = wave & 1;
  const int m0 = blockIdx.y * 128, n0 = blockIdx.x * 128;

  f32x4 acc[4][4] = {};
  const int pbase = wave*2048 + lane*16;   // this wave's staging bytes

  for (int kb = 0; kb < K; kb += 32) {
    __syncthreads();
#pragma unroll
    for (int i = 0; i < 2; i++) {
      int p = pbase + i*1024;
      int row = p >> 6, cb = p & 63;       // LDS row-major [128][32] bf16 (64B rows)
      gload16((const char*)A + ((size_t)(m0+row)*K + kb)*2 + cb, (char*)As + p);
      gload16((const char*)B + ((size_t)(n0+row)*K + kb)*2 + cb, (char*)Bs + p);
    }
    __syncthreads();
    bf16x8 af[4], bfr[4];
#pragma unroll
    for (int f = 0; f < 4; f++) {
      af[f]  = *(const bf16x8*)(As + (wr*64 + f*16 + l15)*32 + lg*8);
      bfr[f] = *(const bf16x8*)(Bs + (wc*64 + f*16 + l15)*32 + lg*8);
    }
#pragma unroll
    for (int fm = 0; fm < 4; fm++)
#pragma unroll
      for (int fn = 0; fn < 4; fn++)
        acc[fm][fn] = __builtin_amdgcn_mfma_f32_16x16x32_bf16(af[fm], bfr[fn],
                                                              acc[fm][fn], 0, 0, 0);
  }

  // D layout: col = lane&15, row = (lane>>4)*4 + reg   [m89-verified]
  if (EPI == 0) {
    const int c0 = n0 + wc*64;           // 64-aligned -> single (t,h) per wave
    const int t = c0 / DIM;
    const int hcol = (c0 % DIM) >> 6;
#pragma unroll
    for (int fm = 0; fm < 4; fm++) {
      const int gm0 = m0 + wr*64 + fm*16 + (lg<<2);
      const int b = gm0 >> 11, nn0 = gm0 & 2047;
      const size_t bh = (size_t)b*NH + hcol;
#pragma unroll
      for (int fn = 0; fn < 4; fn++) {
        const int d = fn*16 + l15;
        if (t == 0) {
#pragma unroll
          for (int r = 0; r < 4; r++)
            qv[(bh*N_ + nn0 + r)*HD + d] = (bf16)(acc[fm][fn][r] * 0.125f);
        } else if (t == 1) {
#pragma unroll
          for (int r = 0; r < 4; r++)
            kv_[(bh*N_ + nn0 + r)*HD + d] = (bf16)acc[fm][fn][r];
        } else {
          bf16x4 pk = { (bf16)acc[fm][fn][0], (bf16)acc[fm][fn][1],
                        (bf16)acc[fm][fn][2], (bf16)acc[fm][fn][3] };
          *(bf16x4*)(vt + (bh*HD + d)*N_ + nn0) = pk;   // V^T: [bh][d][n]
        }
      }
    }
  } else {
#pragma unroll
    for (int fn = 0; fn < 4; fn++) {
      const int c = n0 + wc*64 + fn*16 + l15;
      const float bias = bprj[c];
#pragma unroll
      for (int fm = 0; fm < 4; fm++) {
        const int gm0 = m0 + wr*64 + fm*16 + (lg<<2);
#pragma unroll
        for (int r = 0; r < 4; r++)
          out[(size_t)(gm0 + r)*DIM + c] = acc[fm][fn][r] + bias;
      }
    }
  }
}

// ---------------------------------------------------------------- attention
// grid (N/128, BH). 4 waves x 32 q-rows. KV tiles of 64.
// K tile LDS [64 kk][64 d], V^T tile LDS [64 d][64 kk]; both rows = 128B with
// XOR swizzle  cb_phys = cb ^ ((row&7)<<4)  applied on global source AND reads.
__global__ __launch_bounds__(256)
void attn_fwd(const bf16* __restrict__ Q, const bf16* __restrict__ Kb,
              const bf16* __restrict__ Vt, bf16* __restrict__ AO) {
  __shared__ __align__(16) bf16 Ks[64*64];
  __shared__ __align__(16) bf16 Vs[64*64];
  __shared__ __align__(16) bf16 Ps[4*32*64];   // per-wave P [32 q][64 kk]
  const int tid = threadIdx.x;
  const int wave = tid >> 6, lane = tid & 63;
  const int l15 = lane & 15, lg = lane >> 4;
  const int bh = blockIdx.y;
  const int b = bh / NH, h = bh % NH;
  const int q0 = blockIdx.x*128 + wave*32;

  // Q fragments in registers (scale already folded into Q by GEMM epilogue)
  const bf16* Qbase = Q + (size_t)bh*N_*HD;
  bf16x8 qf[2][2];
#pragma unroll
  for (int fq = 0; fq < 2; fq++)
#pragma unroll
    for (int ks = 0; ks < 2; ks++)
      qf[fq][ks] = *(const bf16x8*)(Qbase + (size_t)(q0 + fq*16 + l15)*HD + ks*32 + lg*8);

  f32x4 O[2][4] = {};
  float mrow[2][4], lrow[2][4];
#pragma unroll
  for (int fq = 0; fq < 2; fq++)
#pragma unroll
    for (int r = 0; r < 4; r++) { mrow[fq][r] = -INFINITY; lrow[fq][r] = 0.f; }

  bf16* Pw = Ps + wave*32*64;
  const char* Kg = (const char*)(Kb + (size_t)bh*N_*HD);
  const char* Vg = (const char*)(Vt + (size_t)bh*HD*N_);
  const int pbase = wave*2048 + lane*16;

  for (int kv = 0; kv < N_; kv += 64) {
    __syncthreads();
#pragma unroll
    for (int i = 0; i < 2; i++) {
      int p = pbase + i*1024;
      int r = p >> 7, cbp = p & 127;
      int cb = cbp ^ ((r & 7) << 4);               // inverse-swizzled source
      gload16(Kg + (size_t)(kv + r)*128 + cb, (char*)Ks + p);
      gload16(Vg + (size_t)r*(N_*2) + kv*2 + cb, (char*)Vs + p);
    }
    __syncthreads();

    // S = Q * K^T  (scale folded into Q)
    f32x4 s[2][4] = {};
#pragma unroll
    for (int ks = 0; ks < 2; ks++) {
      bf16x8 kf[4];
#pragma unroll
      for (int fk = 0; fk < 4; fk++) {
        int r = fk*16 + l15;
        int cb = (ks*64 + lg*16) ^ ((r & 7) << 4);
        kf[fk] = *(const bf16x8*)((const char*)Ks + r*128 + cb);
      }
#pragma unroll
      for (int fq = 0; fq < 2; fq++)
#pragma unroll
        for (int fk = 0; fk < 4; fk++)
          s[fq][fk] = __builtin_amdgcn_mfma_f32_16x16x32_bf16(qf[fq][ks], kf[fk],
                                                              s[fq][fk], 0, 0, 0);
    }

    // online softmax; write P (bf16) into per-wave swizzled LDS
#pragma unroll
    for (int fq = 0; fq < 2; fq++)
#pragma unroll
      for (int r = 0; r < 4; r++) {
        float mx = fmaxf(fmaxf(s[fq][0][r], s[fq][1][r]),
                         fmaxf(s[fq][2][r], s[fq][3][r]));
        mx = fmaxf(mx, __shfl_xor(mx, 1));
        mx = fmaxf(mx, __shfl_xor(mx, 2));
        mx = fmaxf(mx, __shfl_xor(mx, 4));
        mx = fmaxf(mx, __shfl_xor(mx, 8));
        const float mn = fmaxf(mrow[fq][r], mx);
        const float c = __expf(mrow[fq][r] - mn);   // exp(-inf)=0 on first tile
        mrow[fq][r] = mn;
        const int row = fq*16 + (lg<<2) + r;        // q-row within wave's 32
        float rs = 0.f;
#pragma unroll
        for (int fk = 0; fk < 4; fk++) {
          float p = __expf(s[fq][fk][r] - mn);
          rs += p;
          int cb = ((fk*16 + l15) << 1) ^ ((row & 7) << 4);
          *(bf16*)((char*)Pw + row*128 + cb) = (bf16)p;
        }
        rs += __shfl_xor(rs, 1);
        rs += __shfl_xor(rs, 2);
        rs += __shfl_xor(rs, 4);
        rs += __shfl_xor(rs, 8);
        lrow[fq][r] = lrow[fq][r]*c + rs;
#pragma unroll
        for (int fd = 0; fd < 4; fd++) O[fq][fd][r] *= c;
      }

    // O += P * V   (A = P from LDS, B = V^T rows -> kk-contiguous)
#pragma unroll
    for (int ks = 0; ks < 2; ks++) {
      bf16x8 pa[2];
#pragma unroll
      for (int fq = 0; fq < 2; fq++) {
        int row = fq*16 + l15;
        int cb = (ks*64 + lg*16) ^ ((row & 7) << 4);
        pa[fq] = *(const bf16x8*)((const char*)Pw + row*128 + cb);
      }
      bf16x8 vb[4];
#pragma unroll
      for (int fd = 0; fd < 4; fd++) {
        int r = fd*16 + l15;
        int cb = (ks*64 + lg*16) ^ ((r & 7) << 4);
        vb[fd] = *(const bf16x8*)((const char*)Vs + r*128 + cb);
      }
#pragma unroll
      for (int fq = 0; fq < 2; fq++)
#pragma unroll
        for (int fd = 0; fd < 4; fd++)
          O[fq][fd] = __builtin_amdgcn_mfma_f32_16x16x32_bf16(pa[fq], vb[fd],
                                                              O[fq][fd], 0, 0, 0);
    }
  }

  // normalize + store attention output as proj-GEMM input layout [token][768]
#pragma unroll
  for (int fq = 0; fq < 2; fq++)
#pragma unroll
    for (int r = 0; r < 4; r++) {
      const float inv = 1.f / lrow[fq][r];
      const int nn = q0 + fq*16 + (lg<<2) + r;
#pragma unroll
      for (int fd = 0; fd < 4; fd++) {
        const int d = fd*16 + l15;
        AO[((size_t)b*N_ + nn)*DIM + h*HD + d] = (bf16)(O[fq][fd][r] * inv);
      }
    }
}

// ---------------------------------------------------------------- launch
extern "C" void kernel_launch(void* const* d_in, const int* in_sizes, int n_in,
                              void* d_out, int out_size, void* d_ws, size_t ws_size,
                              hipStream_t stream) {
  const float* x     = (const float*)d_in[0];
  // d_in[1] = xpos : unused by the reference
  const float* wqkv  = (const float*)d_in[2];
  const float* wproj = (const float*)d_in[3];
  const float* bproj = (const float*)d_in[4];
  float* out = (float*)d_out;

  char* ws = (char*)d_ws;            // needs ~67.6 MB
  bf16* xb    = (bf16*)ws;  ws += (size_t)M_*DIM*2;        // 12.6 MB
  bf16* wqkvb = (bf16*)ws;  ws += (size_t)3*DIM*DIM*2;     //  3.5 MB
  bf16* wprojb= (bf16*)ws;  ws += (size_t)DIM*DIM*2;       //  1.2 MB
  bf16* qb    = (bf16*)ws;  ws += (size_t)BH_*N_*HD*2;     // 12.6 MB
  bf16* kb    = (bf16*)ws;  ws += (size_t)BH_*N_*HD*2;     // 12.6 MB
  bf16* vtb   = (bf16*)ws;  ws += (size_t)BH_*HD*N_*2;     // 12.6 MB
  bf16* aob   = (bf16*)ws;  ws += (size_t)M_*DIM*2;        // 12.6 MB

  convert_all<<<dim3(2048), dim3(256), 0, stream>>>(
      (const float4*)x, (const float4*)wqkv, (const float4*)wproj,
      (bf16x4*)xb, (bf16x4*)wqkvb, (bf16x4*)wprojb);

  gemm_bt<0><<<dim3(3*DIM/128, M_/128), dim3(256), 0, stream>>>(
      xb, wqkvb, qb, kb, vtb, nullptr, nullptr);

  attn_fwd<<<dim3(N_/128, BH_), dim3(256), 0, stream>>>(qb, kb, vtb, aob);

  gemm_bt<1><<<dim3(DIM/128, M_/128), dim3(256), 0, stream>>>(
      aob, wprojb, nullptr, nullptr, nullptr, bproj, out);
}

// Round 4
// 267.183 us; speedup vs baseline: 1.2142x; 1.2142x over previous
//
#include <hip/hip_runtime.h>
#include <math.h>

typedef __bf16 bf16;
typedef __attribute__((ext_vector_type(4))) __bf16 bf16x4;
typedef __attribute__((ext_vector_type(8))) __bf16 bf16x8;
typedef __attribute__((ext_vector_type(4))) float f32x4;
typedef __attribute__((ext_vector_type(4))) unsigned int u32x4;

#define AS1 __attribute__((address_space(1)))
#define AS3 __attribute__((address_space(3)))

__device__ __forceinline__ void gload16(const void* g, void* l) {
  __builtin_amdgcn_global_load_lds((const AS1 void*)g, (AS3 void*)l, 16, 0, 0);
}

__device__ __forceinline__ unsigned int pack2bf(float lo, float hi) {
  union { unsigned int u; __bf16 h[2]; } w;
  w.h[0] = (bf16)lo; w.h[1] = (bf16)hi;
  return w.u;
}

#define DIM 768
#define NH  12
#define HD  64
#define B_  4
#define N_  2048
#define M_  (B_*N_)   // 8192 tokens
#define BH_ (B_*NH)   // 48 (b,h) pairs

// ---------------------------------------------------------------- convert
__global__ void convert_all(const float4* __restrict__ x,
                            const float4* __restrict__ wq,
                            const float4* __restrict__ wp,
                            bf16x4* __restrict__ xb,
                            bf16x4* __restrict__ wqb,
                            bf16x4* __restrict__ wpb) {
  const int nx = M_*DIM/4, nq = 3*DIM*DIM/4, np = DIM*DIM/4;
  const int total = nx + nq + np;
  for (int i = blockIdx.x*blockDim.x + threadIdx.x; i < total;
       i += gridDim.x*blockDim.x) {
    float4 v; bf16x4* dst;
    if (i < nx)           { v = x[i];         dst = xb  + i;         }
    else if (i < nx + nq) { v = wq[i-nx];     dst = wqb + (i-nx);    }
    else                  { v = wp[i-nx-nq];  dst = wpb + (i-nx-nq); }
    bf16x4 o = { (bf16)v.x, (bf16)v.y, (bf16)v.z, (bf16)v.w };
    *dst = o;
  }
}

// ---------------------------------------------------------------- GEMM (B^T)
template<int EPI>
__global__ __launch_bounds__(256)
void gemm_bt(const bf16* __restrict__ A, const bf16* __restrict__ B,
             bf16* __restrict__ qv, bf16* __restrict__ kv_, bf16* __restrict__ vt,
             const float* __restrict__ bprj, float* __restrict__ out) {
  constexpr int K = DIM;
  __shared__ __align__(16) bf16 As[128*32];
  __shared__ __align__(16) bf16 Bs[128*32];
  const int tid = threadIdx.x;
  const int wave = tid >> 6, lane = tid & 63;
  const int l15 = lane & 15, lg = lane >> 4;
  const int wr = wave >> 1, wc = wave & 1;
  const int m0 = blockIdx.y * 128, n0 = blockIdx.x * 128;

  f32x4 acc[4][4] = {};
  const int pbase = wave*2048 + lane*16;

  for (int kb = 0; kb < K; kb += 32) {
    __syncthreads();
#pragma unroll
    for (int i = 0; i < 2; i++) {
      int p = pbase + i*1024;
      int row = p >> 6, cb = p & 63;
      gload16((const char*)A + ((size_t)(m0+row)*K + kb)*2 + cb, (char*)As + p);
      gload16((const char*)B + ((size_t)(n0+row)*K + kb)*2 + cb, (char*)Bs + p);
    }
    __syncthreads();
    bf16x8 af[4], bfr[4];
#pragma unroll
    for (int f = 0; f < 4; f++) {
      af[f]  = *(const bf16x8*)(As + (wr*64 + f*16 + l15)*32 + lg*8);
      bfr[f] = *(const bf16x8*)(Bs + (wc*64 + f*16 + l15)*32 + lg*8);
    }
#pragma unroll
    for (int fm = 0; fm < 4; fm++)
#pragma unroll
      for (int fn = 0; fn < 4; fn++)
        acc[fm][fn] = __builtin_amdgcn_mfma_f32_16x16x32_bf16(af[fm], bfr[fn],
                                                              acc[fm][fn], 0, 0, 0);
  }

  if (EPI == 0) {
    const int c0 = n0 + wc*64;
    const int t = c0 / DIM;
    const int hcol = (c0 % DIM) >> 6;
#pragma unroll
    for (int fm = 0; fm < 4; fm++) {
      const int gm0 = m0 + wr*64 + fm*16 + (lg<<2);
      const int b = gm0 >> 11, nn0 = gm0 & 2047;
      const size_t bh = (size_t)b*NH + hcol;
#pragma unroll
      for (int fn = 0; fn < 4; fn++) {
        const int d = fn*16 + l15;
        if (t == 0) {
#pragma unroll
          for (int r = 0; r < 4; r++)
            qv[(bh*N_ + nn0 + r)*HD + d] = (bf16)(acc[fm][fn][r] * 0.125f);
        } else if (t == 1) {
#pragma unroll
          for (int r = 0; r < 4; r++)
            kv_[(bh*N_ + nn0 + r)*HD + d] = (bf16)acc[fm][fn][r];
        } else {
          bf16x4 pk = { (bf16)acc[fm][fn][0], (bf16)acc[fm][fn][1],
                        (bf16)acc[fm][fn][2], (bf16)acc[fm][fn][3] };
          *(bf16x4*)(vt + (bh*HD + d)*N_ + nn0) = pk;
        }
      }
    }
  } else {
#pragma unroll
    for (int fn = 0; fn < 4; fn++) {
      const int c = n0 + wc*64 + fn*16 + l15;
      const float bias = bprj[c];
#pragma unroll
      for (int fm = 0; fm < 4; fm++) {
        const int gm0 = m0 + wr*64 + fm*16 + (lg<<2);
#pragma unroll
        for (int r = 0; r < 4; r++)
          out[(size_t)(gm0 + r)*DIM + c] = acc[fm][fn][r] + bias;
      }
    }
  }
}

// ---------------------------------------------------------------- attention
// Swapped-QK^T flash attention. grid (N/128, BH). 4 waves x 32 q-rows, KVBLK=64,
// double-buffered K/V staging (stage t+1 issued before computing t).
__global__ __launch_bounds__(256)
void attn_fwd(const bf16* __restrict__ Q, const bf16* __restrict__ Kb,
              const bf16* __restrict__ Vt, bf16* __restrict__ AO) {
  __shared__ __align__(16) bf16 Ks[2][64*64];
  __shared__ __align__(16) bf16 Vs[2][64*64];
  const int tid = threadIdx.x;
  const int wave = tid >> 6, lane = tid & 63;
  const int l15 = lane & 15, lg = lane >> 4;
  const int bh = blockIdx.y;
  const int b = bh / NH, h = bh % NH;
  const int q0 = blockIdx.x*128 + wave*32;

  const bf16* Qbase = Q + (size_t)bh*N_*HD;
  bf16x8 qf[2][2];
#pragma unroll
  for (int fq = 0; fq < 2; fq++)
#pragma unroll
    for (int ks = 0; ks < 2; ks++)
      qf[fq][ks] = *(const bf16x8*)(Qbase + (size_t)(q0 + fq*16 + l15)*HD + ks*32 + lg*8);

  f32x4 Ot[2][4] = {};                 // O^T: row=d (reg axis), col=q=l15
  float m_[2] = { -INFINITY, -INFINITY };
  float l_[2] = { 0.f, 0.f };

  const char* Kg = (const char*)(Kb + (size_t)bh*N_*HD);
  const char* Vg = (const char*)(Vt + (size_t)bh*HD*N_);
  const int pbase = wave*2048 + lane*16;
  const bool lower = (lane < 32);
  const bool q03 = (lg == 0) || (lg == 3);

#define STAGE(buf, kv)                                                      \
  {                                                                         \
    _Pragma("unroll")                                                       \
    for (int i = 0; i < 2; i++) {                                           \
      int p = pbase + i*1024;                                               \
      int r = p >> 7, cbp = p & 127;                                        \
      int cb = cbp ^ ((r & 7) << 4);                                        \
      gload16(Kg + (size_t)((kv) + r)*128 + cb, (char*)Ks[buf] + p);        \
      gload16(Vg + (size_t)r*(N_*2) + (kv)*2 + cb, (char*)Vs[buf] + p);     \
    }                                                                       \
  }

  STAGE(0, 0);

  for (int t = 0; t < N_/64; ++t) {
    __syncthreads();                       // drains own vmcnt -> tile t ready
    if (t + 1 < N_/64) STAGE((t+1)&1, (t+1)*64);
    const char* Kc = (const char*)Ks[t&1];
    const char* Vc = (const char*)Vs[t&1];

    // S^T = K * Q^T
    f32x4 s[2][4] = {};
#pragma unroll
    for (int ks = 0; ks < 2; ks++) {
      bf16x8 kf[4];
#pragma unroll
      for (int fk = 0; fk < 4; fk++) {
        int r = fk*16 + l15;
        int cb = (ks*64 + lg*16) ^ ((r & 7) << 4);
        kf[fk] = *(const bf16x8*)(Kc + r*128 + cb);
      }
#pragma unroll
      for (int fq = 0; fq < 2; fq++)
#pragma unroll
        for (int fk = 0; fk < 4; fk++)
          s[fq][fk] = __builtin_amdgcn_mfma_f32_16x16x32_bf16(kf[fk], qf[fq][ks],
                                                              s[fq][fk], 0, 0, 0);
    }

    // softmax + in-register P -> B-operand words paw[fq][ks][0..3]
    unsigned int paw[2][2][4];
#pragma unroll
    for (int fq = 0; fq < 2; fq++) {
      float mx = s[fq][0][0];
#pragma unroll
      for (int fk = 0; fk < 4; fk++)
#pragma unroll
        for (int r = 0; r < 4; r++) mx = fmaxf(mx, s[fq][fk][r]);
      mx = fmaxf(mx, __shfl_xor(mx, 16));
      mx = fmaxf(mx, __shfl_xor(mx, 32));
      if (!__all(mx - m_[fq] <= 6.0f)) {       // defer-max
        float mn = fmaxf(m_[fq], mx);
        float c = __expf(m_[fq] - mn);
        m_[fq] = mn; l_[fq] *= c;
#pragma unroll
        for (int fd = 0; fd < 4; fd++) Ot[fq][fd] *= c;
      }
      float pe[4][4]; float rs = 0.f;
#pragma unroll
      for (int fk = 0; fk < 4; fk++)
#pragma unroll
        for (int r = 0; r < 4; r++) {
          pe[fk][r] = __expf(s[fq][fk][r] - m_[fq]);
          rs += pe[fk][r];
        }
      rs += __shfl_xor(rs, 16);
      rs += __shfl_xor(rs, 32);
      l_[fq] += rs;

      unsigned int pk[4][2];
#pragma unroll
      for (int fk = 0; fk < 4; fk++)
#pragma unroll
        for (int rp = 0; rp < 2; rp++)
          pk[fk][rp] = pack2bf(pe[fk][2*rp], pe[fk][2*rp+1]);

      unsigned int Eo[2][2], Er[2][2], rB[2][2];
#pragma unroll
      for (int fh = 0; fh < 2; fh++)
#pragma unroll
        for (int rp = 0; rp < 2; rp++) {
          unsigned int vA = lower ? pk[2*fh+1][rp] : pk[2*fh][rp];
          Er[fh][rp] = __shfl_xor((int)vA, 32);
          Eo[fh][rp] = lower ? pk[2*fh][rp] : pk[2*fh+1][rp];
        }
#pragma unroll
      for (int fh = 0; fh < 2; fh++)
#pragma unroll
        for (int rp = 0; rp < 2; rp++) {
          unsigned int vB = q03 ? Er[fh][rp] : Eo[fh][rp];
          rB[fh][rp] = __shfl_xor((int)vB, 16);
        }
#pragma unroll
      for (int ks = 0; ks < 2; ks++) {
#pragma unroll
        for (int rp = 0; rp < 2; rp++) {
          paw[fq][ks][rp] = (lg == 0) ? Eo[ks][rp] :
                            (lg == 1) ? rB[ks][rp] :
                            (lg == 2) ? Er[ks][rp] : rB[ks][rp];
          paw[fq][ks][2+rp] = (lg == 0) ? rB[ks][rp] :
                              (lg == 1) ? Er[ks][rp] :
                              (lg == 2) ? rB[ks][rp] : Eo[ks][rp];
        }
      }
    }

    // O^T += V^T * P
#pragma unroll
    for (int ks = 0; ks < 2; ks++) {
      bf16x8 vb[4];
#pragma unroll
      for (int fd = 0; fd < 4; fd++) {
        int r = fd*16 + l15;
        int cb = (ks*64 + lg*16) ^ ((r & 7) << 4);
        vb[fd] = *(const bf16x8*)(Vc + r*128 + cb);
      }
#pragma unroll
      for (int fq = 0; fq < 2; fq++) {
        u32x4 tw = { paw[fq][ks][0], paw[fq][ks][1], paw[fq][ks][2], paw[fq][ks][3] };
        bf16x8 pa = __builtin_bit_cast(bf16x8, tw);
#pragma unroll
        for (int fd = 0; fd < 4; fd++)
          Ot[fq][fd] = __builtin_amdgcn_mfma_f32_16x16x32_bf16(vb[fd], pa,
                                                               Ot[fq][fd], 0, 0, 0);
      }
    }
  }

#pragma unroll
  for (int fq = 0; fq < 2; fq++) {
    const float inv = 1.f / l_[fq];
    const int qrow = q0 + fq*16 + l15;
#pragma unroll
    for (int fd = 0; fd < 4; fd++) {
      bf16x4 pk4 = { (bf16)(Ot[fq][fd][0]*inv), (bf16)(Ot[fq][fd][1]*inv),
                     (bf16)(Ot[fq][fd][2]*inv), (bf16)(Ot[fq][fd][3]*inv) };
      *(bf16x4*)(AO + ((size_t)b*N_ + qrow)*DIM + h*HD + fd*16 + lg*4) = pk4;
    }
  }
#undef STAGE
}

// ---------------------------------------------------------------- launch
extern "C" void kernel_launch(void* const* d_in, const int* in_sizes, int n_in,
                              void* d_out, int out_size, void* d_ws, size_t ws_size,
                              hipStream_t stream) {
  const float* x     = (const float*)d_in[0];
  // d_in[1] = xpos : unused by the reference
  const float* wqkv  = (const float*)d_in[2];
  const float* wproj = (const float*)d_in[3];
  const float* bproj = (const float*)d_in[4];
  float* out = (float*)d_out;

  char* ws = (char*)d_ws;
  bf16* xb    = (bf16*)ws;  ws += (size_t)M_*DIM*2;
  bf16* wqkvb = (bf16*)ws;  ws += (size_t)3*DIM*DIM*2;
  bf16* wprojb= (bf16*)ws;  ws += (size_t)DIM*DIM*2;
  bf16* qb    = (bf16*)ws;  ws += (size_t)BH_*N_*HD*2;
  bf16* kb    = (bf16*)ws;  ws += (size_t)BH_*N_*HD*2;
  bf16* vtb   = (bf16*)ws;  ws += (size_t)BH_*HD*N_*2;
  bf16* aob   = (bf16*)ws;  ws += (size_t)M_*DIM*2;

  convert_all<<<dim3(2048), dim3(256), 0, stream>>>(
      (const float4*)x, (const float4*)wqkv, (const float4*)wproj,
      (bf16x4*)xb, (bf16x4*)wqkvb, (bf16x4*)wprojb);

  gemm_bt<0><<<dim3(3*DIM/128, M_/128), dim3(256), 0, stream>>>(
      xb, wqkvb, qb, kb, vtb, nullptr, nullptr);

  attn_fwd<<<dim3(N_/128, BH_), dim3(256), 0, stream>>>(qb, kb, vtb, aob);

  gemm_bt<1><<<dim3(DIM/128, M_/128), dim3(256), 0, stream>>>(
      aob, wprojb, nullptr, nullptr, nullptr, bproj, out);
}